// Round 5
// baseline (388.545 us; speedup 1.0000x reference)
//
#include <hip/hip_runtime.h>
#include <hip/hip_bf16.h>

// B=64, T=2048, D=784, N1=100, N2=10, dt=0.04
// Pipeline:
//   prep_w6    : W1 -> exact 3x bf16 split (h/m/l), padded per-K-tile image (32768 B/tile)
//   gemm1_k    : z1 = batch @ W1^T, 6-term exact bf16 MFMA. BM=512, 8 waves, rt=4.
//                A: global->reg->frags (no LDS). W: reg-staged 2-buf LDS,
//                single raw s_barrier/iter (lgkmcnt only; vmem stays in flight).
//   fused_scan : scan1 + gemm2 + scan2, raw barriers (z prefetch survives),
//                gemm2 on 384 threads with sgpr-uniform W2.
//
// ws: Wg 819200 B | z1p 131072*100 f32 (52.4 MB). Total ~53.3 MB.

#define FHN_DT 0.04f

typedef __attribute__((ext_vector_type(8))) short          bf16x8;
typedef __attribute__((ext_vector_type(4))) float          f32x4;
typedef __attribute__((ext_vector_type(8))) unsigned short ushort8;

__device__ __forceinline__ unsigned short f2bf(float x) {
    unsigned u = __float_as_uint(x);
    u += 0x7fffu + ((u >> 16) & 1u);      // RNE
    return (unsigned short)(u >> 16);
}
__device__ __forceinline__ float bf2f(unsigned short h) {
    return __uint_as_float(((unsigned)h) << 16);
}

__device__ __forceinline__ void sync_lds() {
    asm volatile("s_waitcnt lgkmcnt(0)" ::: "memory");
    __builtin_amdgcn_s_barrier();
    asm volatile("" ::: "memory");
}

// ---------------- prep: W1 (100x784) -> padded tiled 3-term split image ----------------
// Image: [kt=25] x 16384 shorts; within tile: [term=3][n=112][40 shorts], rest pad=0.
__global__ void prep_w6(const float* __restrict__ W1, unsigned short* __restrict__ Wg) {
    int idx = blockIdx.x * 256 + threadIdx.x;
    if (idx >= 409600) return;
    int kt  = idx >> 14;
    int rem = idx & 16383;
    unsigned short outv = 0;
    if (rem < 13440) {
        int term = rem / 4480;
        int r2   = rem % 4480;
        int n    = r2 / 40;
        int sh   = r2 % 40;
        int k    = kt * 32 + sh;
        float v = (n < 100 && sh < 32 && k < 784) ? W1[n * 784 + k] : 0.0f;
        unsigned short h = f2bf(v);
        float r1 = v - bf2f(h);
        unsigned short m = f2bf(r1);
        float rr = r1 - bf2f(m);
        unsigned short l = f2bf(rr);
        outv = (term == 0) ? h : ((term == 1) ? m : l);
    }
    Wg[idx] = outv;
}

// ---------------- GEMM1: 6-term exact bf16 split, BM=512, BK=32, 8 waves ----------------
__global__ __launch_bounds__(512, 2) void gemm1_k(const float* __restrict__ A,
                                                  const unsigned short* __restrict__ Wg,
                                                  float* __restrict__ z1p) {
    __shared__ __align__(16) unsigned short Wl[2][16384];
    const int tid  = threadIdx.x;
    const int w    = tid >> 6;
    const int lane = tid & 63;
    const int ln   = lane & 15;
    const int kg   = lane >> 4;                 // 0..3, k-slice = kg*8
    const long row0 = (long)blockIdx.x * 512;

    const float* arow[4];
#pragma unroll
    for (int rt = 0; rt < 4; ++rt)
        arow[rt] = A + (row0 + w * 64 + rt * 16 + ln) * 784 + kg * 8;

    f32x4 acc[4][7] = {};
    float afp[4][8];
    ushort8 wreg[4];

    // ---- prologue: tile 0 into regs ----
#pragma unroll
    for (int rt = 0; rt < 4; ++rt) {
        *(float4*)&afp[rt][0] = *(const float4*)(arow[rt]);
        *(float4*)&afp[rt][4] = *(const float4*)(arow[rt] + 4);
    }
#pragma unroll
    for (int j = 0; j < 4; ++j)
        wreg[j] = *(const ushort8*)(Wg + (j * 8192 + tid * 16) / 2);

    for (int kt = 0; kt < 25; ++kt) {
        // wait this tile's loads (issued one iter ago; long done in steady state)
        asm volatile("s_waitcnt vmcnt(0)" ::: "memory");

        // ---- split A fp32 -> exact h/m/l bf16 frags (registers only) ----
        bf16x8 ah[4], am[4], al[4];
#pragma unroll
        for (int rt = 0; rt < 4; ++rt) {
#pragma unroll
            for (int e = 0; e < 8; ++e) {
                float a = afp[rt][e];
                unsigned short h = f2bf(a);
                float r1 = a - bf2f(h);
                unsigned short m = f2bf(r1);
                float r2 = r1 - bf2f(m);
                unsigned short l = f2bf(r2);
                ah[rt][e] = (short)h;
                am[rt][e] = (short)m;
                al[rt][e] = (short)l;
            }
        }

        // ---- stage W tile kt (from regs) into LDS buffer kt&1 ----
        unsigned short* buf = &Wl[kt & 1][0];
#pragma unroll
        for (int j = 0; j < 4; ++j)
            *(ushort8*)(buf + (j * 8192 + tid * 16) / 2) = wreg[j];

        // ---- issue prefetch for tile kt+1 (stays in flight across barrier+compute) ----
        if (kt < 24) {
            const int ktn = kt + 1;
            const int kbase = ktn * 32 + kg * 8;
            const bool ok = (kbase < 784);
#pragma unroll
            for (int rt = 0; rt < 4; ++rt) {
                float4 v0 = make_float4(0.f, 0.f, 0.f, 0.f);
                float4 v1 = v0;
                if (ok) {
                    v0 = *(const float4*)(arow[rt] + ktn * 32);
                    v1 = *(const float4*)(arow[rt] + ktn * 32 + 4);
                }
                *(float4*)&afp[rt][0] = v0;
                *(float4*)&afp[rt][4] = v1;
            }
#pragma unroll
            for (int j = 0; j < 4; ++j)
                wreg[j] = *(const ushort8*)(Wg + (size_t)ktn * 16384 + (j * 8192 + tid * 16) / 2);
        }

        // ---- single barrier: LDS writes visible; vmem NOT drained ----
        sync_lds();

        // ---- compute tile kt: 7 col-tiles x 4 row-tiles x 6 exact-split terms ----
        const unsigned short* cb = &Wl[kt & 1][0];
#pragma unroll
        for (int ct = 0; ct < 7; ++ct) {
            const unsigned short* pw = cb + (ct * 16 + ln) * 40 + kg * 8;
            bf16x8 bh = *(const bf16x8*)(pw);
            bf16x8 bm = *(const bf16x8*)(pw + 4480);
            bf16x8 bl = *(const bf16x8*)(pw + 8960);
#pragma unroll
            for (int rt = 0; rt < 4; ++rt) {
                f32x4 c = acc[rt][ct];
                c = __builtin_amdgcn_mfma_f32_16x16x32_bf16(ah[rt], bh, c, 0, 0, 0);
                c = __builtin_amdgcn_mfma_f32_16x16x32_bf16(ah[rt], bm, c, 0, 0, 0);
                c = __builtin_amdgcn_mfma_f32_16x16x32_bf16(am[rt], bh, c, 0, 0, 0);
                c = __builtin_amdgcn_mfma_f32_16x16x32_bf16(ah[rt], bl, c, 0, 0, 0);
                c = __builtin_amdgcn_mfma_f32_16x16x32_bf16(al[rt], bh, c, 0, 0, 0);
                c = __builtin_amdgcn_mfma_f32_16x16x32_bf16(am[rt], bm, c, 0, 0, 0);
                acc[rt][ct] = c;
            }
        }
    }

    // ---- epilogue: C/D map col = lane&15, row = kg*4 + r ----
#pragma unroll
    for (int ct = 0; ct < 7; ++ct) {
        int n = ct * 16 + ln;
        if (n < 100) {
#pragma unroll
            for (int rt = 0; rt < 4; ++rt) {
                long rg = row0 + w * 64 + rt * 16 + kg * 4;
                float* p = z1p + rg * 100 + n;
#pragma unroll
                for (int r = 0; r < 4; ++r) p[r * 100] = acc[rt][ct][r];
            }
        }
    }
}

// ---------------- fused scan1 + gemm2 + scan2 ----------------
// 64 blocks (one per batch b), 512 threads:
//   tid 0..99   : scan1 lanes (n = tid), 3-deep z prefetch (48 steps ahead)
//   tid 100..109: scan2 lanes (m = tid-100), chunk i-2 (same SIMT FHN core)
//   tid 128..511: gemm2 (chunk i-1; 3 threads/row, W2 via uniform sgpr loads)
//                 + V2 copy-out (chunk i-3)
// LDS (floats): V1s[2][128][116] @0 (cols 0-99 V1, 100-109 V2)
//               z2s[2][128][12] @29696 ; total 32768 floats = 128 KB
__global__ __launch_bounds__(512) void fused_scan(const float* __restrict__ z1p,
                                                  const float* __restrict__ W2,
                                                  float* __restrict__ out) {
    __shared__ float fsm[32768];
    const int tid = threadIdx.x;
    const int b   = blockIdx.x;
    const float dt = FHN_DT;

    float V = 0.f, S = 0.f;
    const float* zb = z1p + (long)b * 2048 * 100 + tid;   // scan1 lanes only
    float z0[16], z1r[16], z2r[16];
    if (tid < 100) {
#pragma unroll
        for (int u = 0; u < 16; ++u) {
            z0[u]  = zb[u * 100];
            z1r[u] = zb[(16 + u) * 100];
            z2r[u] = zb[(32 + u) * 100];
        }
    }

    const int tg = tid - 128;
    int pp = tg >> 7;                                     // wave-uniform for tid>=128
    pp = __builtin_amdgcn_readfirstlane(pp);
    const int r  = tg & 127;
    const int mb = (pp == 0) ? 0 : (pp == 1 ? 4 : 7);
    const int mc = (pp == 0) ? 4 : 3;

    for (int i = 0; i <= 18; ++i) {
        if (tid < 128) {
            bool a1 = (tid < 100) && (i < 16);
            bool a2 = (tid >= 100) && (tid < 110) && (i >= 2) && (i < 18);
            if (a1 || a2) {
                const int cw = i & 1;
#pragma unroll
                for (int sub = 0; sub < 8; ++sub) {
                    float zt[16];
                    if (a1) {
                        int tn = (i * 8 + sub + 3) * 16;
                        if (tn < 2048) {
#pragma unroll
                            for (int u = 0; u < 16; ++u) zt[u] = zb[(tn + u) * 100];
                        }
                    }
                    if (a2) {
#pragma unroll
                        for (int u = 0; u < 16; ++u)
                            z0[u] = fsm[29696 + cw * 1536 + (sub * 16 + u) * 12 + (tid - 100)];
                    }
#pragma unroll
                    for (int u = 0; u < 16; ++u) {
                        int tl = sub * 16 + u;
                        fsm[cw * 14848 + tl * 116 + tid] = V;
                        float z  = z0[u];
                        float V3 = V * V * V;
                        float Vn = fmaf(1.f + dt, V,
                                    fmaf(-dt / 3.f, V3, fmaf(-dt, S, dt * z)));
                        float Sn = fmaf(dt * 0.08f, V + 0.7f - 0.8f * S, S);
                        V = Vn; S = Sn;
                    }
                    if (a1) {
#pragma unroll
                        for (int u = 0; u < 16; ++u) { z0[u] = z1r[u]; z1r[u] = z2r[u]; z2r[u] = zt[u]; }
                    }
                }
            }
        } else {
            if (i >= 1 && i <= 16) {
                const int pb = (i - 1) & 1;
                float acc[4] = {0.f, 0.f, 0.f, 0.f};
                for (int kq = 0; kq < 25; ++kq) {
                    float4 v = *(const float4*)&fsm[pb * 14848 + r * 116 + kq * 4];
#pragma unroll
                    for (int j = 0; j < 4; ++j) {
                        if (j < mc) {
                            const float* wp = W2 + (mb + j) * 100 + kq * 4;  // uniform -> s_load
                            acc[j] = fmaf(v.x, wp[0], acc[j]);
                            acc[j] = fmaf(v.y, wp[1], acc[j]);
                            acc[j] = fmaf(v.z, wp[2], acc[j]);
                            acc[j] = fmaf(v.w, wp[3], acc[j]);
                        }
                    }
                }
#pragma unroll
                for (int j = 0; j < 4; ++j)
                    if (j < mc) fsm[29696 + pb * 1536 + r * 12 + mb + j] = 0.5f * acc[j];
            }
            if (i >= 3) {
                const int pb = (i - 1) & 1;
                float* dst = out + ((long)b * 2048 + (long)(i - 3) * 128 + r) * 10;
#pragma unroll
                for (int j = 0; j < 4; ++j)
                    if (j < mc) dst[mb + j] = fsm[pb * 14848 + r * 116 + 100 + mb + j];
            }
        }
        sync_lds();
    }
}

extern "C" void kernel_launch(void* const* d_in, const int* in_sizes, int n_in,
                              void* d_out, int out_size, void* d_ws, size_t ws_size,
                              hipStream_t stream) {
    const float* batch = (const float*)d_in[0];   // 64*2048*784
    const float* W1    = (const float*)d_in[1];   // 100*784
    const float* W2    = (const float*)d_in[2];   // 10*100
    float* out = (float*)d_out;                   // 64*2048*10

    char* base = (char*)d_ws;
    unsigned short* Wg = (unsigned short*)base;   // 819200 B
    float* z1p = (float*)(base + 819200);         // 131072*100 f32

    prep_w6<<<1600, 256, 0, stream>>>(W1, Wg);
    gemm1_k<<<256, 512, 0, stream>>>(batch, Wg, z1p);
    fused_scan<<<64, 512, 0, stream>>>(z1p, W2, out);
}

// Round 6
// 236.803 us; speedup vs baseline: 1.6408x; 1.6408x over previous
//
#include <hip/hip_runtime.h>
#include <hip/hip_bf16.h>

// B=64, T=2048, D=784, N1=100, N2=10, dt=0.04
// Pipeline:
//   prep_w3    : W1 -> fp16 2-way split (h, r*1024), per-K-tile image [25][2][112][40]
//   gemm1_f    : z1 = batch @ W1^T, 3-term fp16 split MFMA (acc2 scaled 2^-10).
//                BM=64, 256 thr (4 waves, rt=1), W 2-buf LDS (35.8 KB -> 4 blocks/CU),
//                1 lgkmcnt-only barrier/iter; vmem in flight across barrier+compute.
//                grid 2048 -> ~100 KB/CU in flight (MLP fix for round-5's 1.25 TB/s).
//   fused_scan : scan1 + gemm2 + scan2 (round-5 version verbatim; z prefetch 3->4 deep)
//
// ws: Wg 448000 B | z1p 131072*100 f32 (52.4 MB)

#define FHN_DT 0.04f

typedef _Float16 f16x8 __attribute__((ext_vector_type(8)));
typedef __attribute__((ext_vector_type(4))) float          f32x4;
typedef __attribute__((ext_vector_type(8))) unsigned short ushort8;

__device__ __forceinline__ void sync_lds() {
    asm volatile("s_waitcnt lgkmcnt(0)" ::: "memory");
    __builtin_amdgcn_s_barrier();
    asm volatile("" ::: "memory");
}

// ---------------- prep: W1 (100x784) -> tiled fp16 2-term split image ----------------
// Image: [kt=25][term=2][n=112][40 shorts (32 data + 8 pad)]; term1 = (w-h)*1024
__global__ void prep_w3(const float* __restrict__ W1, unsigned short* __restrict__ Wg) {
    int idx = blockIdx.x * 256 + threadIdx.x;
    if (idx >= 224000) return;
    int sh    = idx % 40;
    int rest  = idx / 40;
    int n     = rest % 112;
    int rest2 = rest / 112;
    int term  = rest2 % 2;
    int kt    = rest2 / 2;
    int k = kt * 32 + sh;
    float v = (n < 100 && sh < 32 && k < 784) ? W1[n * 784 + k] : 0.0f;
    _Float16 h = (_Float16)v;
    _Float16 l = (_Float16)((v - (float)h) * 1024.0f);   // scale 2^10: no denormal flush
    Wg[idx] = (term == 0) ? __builtin_bit_cast(unsigned short, h)
                          : __builtin_bit_cast(unsigned short, l);
}

// ---------------- GEMM1: 3-term fp16 split, BM=64, BK=32, 4 waves, rt=1 ----------------
#define GW_TILE 8960     // shorts per K-tile (2 terms x 112 x 40)

__global__ __launch_bounds__(256, 4) void gemm1_f(const float* __restrict__ A,
                                                  const unsigned short* __restrict__ Wg,
                                                  float* __restrict__ z1p) {
    __shared__ __align__(16) unsigned short Wl[2][GW_TILE];   // 35840 B -> 4 blocks/CU
    const int tid  = threadIdx.x;
    const int w    = tid >> 6;
    const int lane = tid & 63;
    const int ln   = lane & 15;
    const int kg   = lane >> 4;                  // k-slice = kg*8
    const long row0 = (long)blockIdx.x * 64;

    const float* arow = A + (row0 + w * 16 + ln) * 784 + kg * 8;

    f32x4 acc1[7] = {};
    f32x4 acc2[7] = {};
    float afp[8];
    ushort8 wreg[5];

    // ---- prologue: tile 0 into regs ----
    *(float4*)&afp[0] = *(const float4*)(arow);
    *(float4*)&afp[4] = *(const float4*)(arow + 4);
#pragma unroll
    for (int j = 0; j < 5; ++j) {
        int off = j * 4096 + tid * 16;
        if (off < 17920) wreg[j] = *(const ushort8*)(Wg + off / 2);
    }

    for (int kt = 0; kt < 25; ++kt) {
        // ---- split A fp32 -> fp16 (h, r*1024) frags, registers only ----
        f16x8 ah, al;
#pragma unroll
        for (int e = 0; e < 8; ++e) {
            float a = afp[e];
            _Float16 h = (_Float16)a;
            float r = (a - (float)h) * 1024.0f;
            ah[e] = h;
            al[e] = (_Float16)r;
        }

        // ---- stage W tile kt (from regs) into LDS buffer kt&1 ----
        unsigned short* buf = &Wl[kt & 1][0];
#pragma unroll
        for (int j = 0; j < 5; ++j) {
            int off = j * 4096 + tid * 16;
            if (off < 17920) *(ushort8*)(buf + off / 2) = wreg[j];
        }

        // ---- issue loads for tile kt+1 (stay in flight across barrier+compute) ----
        if (kt < 24) {
            const int ktn = kt + 1;
            const int kbase = ktn * 32 + kg * 8;
            float4 v0 = make_float4(0.f, 0.f, 0.f, 0.f), v1 = v0;
            if (kbase < 784) {
                v0 = *(const float4*)(arow + ktn * 32);
                v1 = *(const float4*)(arow + ktn * 32 + 4);
            }
            *(float4*)&afp[0] = v0;
            *(float4*)&afp[4] = v1;
#pragma unroll
            for (int j = 0; j < 5; ++j) {
                int off = j * 4096 + tid * 16;
                if (off < 17920)
                    wreg[j] = *(const ushort8*)(Wg + (size_t)ktn * GW_TILE + off / 2);
            }
        }

        // ---- single barrier: LDS writes visible; vmem NOT drained ----
        sync_lds();

        // ---- compute tile kt: 7 col-tiles x 3 terms ----
        const unsigned short* cb = &Wl[kt & 1][0];
#pragma unroll
        for (int ct = 0; ct < 7; ++ct) {
            const unsigned short* pw = cb + (ct * 16 + ln) * 40 + kg * 8;
            f16x8 bh = *(const f16x8*)(pw);
            f16x8 bl = *(const f16x8*)(pw + 4480);
            acc1[ct] = __builtin_amdgcn_mfma_f32_16x16x32_f16(ah, bh, acc1[ct], 0, 0, 0);
            acc2[ct] = __builtin_amdgcn_mfma_f32_16x16x32_f16(ah, bl, acc2[ct], 0, 0, 0);
            acc2[ct] = __builtin_amdgcn_mfma_f32_16x16x32_f16(al, bh, acc2[ct], 0, 0, 0);
        }
    }

    // ---- epilogue: C/D map col = lane&15, row = kg*4 + r ; z = acc1 + acc2/1024 ----
#pragma unroll
    for (int ct = 0; ct < 7; ++ct) {
        int n = ct * 16 + ln;
        if (n < 100) {
            long rg = row0 + w * 16 + kg * 4;
            float* p = z1p + rg * 100 + n;
#pragma unroll
            for (int r = 0; r < 4; ++r)
                p[r * 100] = fmaf(acc2[ct][r], 0.0009765625f, acc1[ct][r]);
        }
    }
}

// ---------------- fused scan1 + gemm2 + scan2 (round-5 structure, 4-deep z prefetch) ----------------
// 64 blocks (one per batch b), 512 threads:
//   tid 0..99   : scan1 lanes (n = tid), 4-deep z prefetch (64 steps ahead)
//   tid 100..109: scan2 lanes (m = tid-100), chunk i-2 (same SIMT FHN core)
//   tid 128..511: gemm2 (chunk i-1; W2 via uniform sgpr loads) + V2 copy-out (chunk i-3)
// LDS (floats): V1s[2][128][116] @0 (cols 0-99 V1, 100-109 V2)
//               z2s[2][128][12] @29696 ; total 32768 floats = 128 KB
__global__ __launch_bounds__(512) void fused_scan(const float* __restrict__ z1p,
                                                  const float* __restrict__ W2,
                                                  float* __restrict__ out) {
    __shared__ float fsm[32768];
    const int tid = threadIdx.x;
    const int b   = blockIdx.x;
    const float dt = FHN_DT;

    float V = 0.f, S = 0.f;
    const float* zb = z1p + (long)b * 2048 * 100 + tid;   // scan1 lanes only
    float z0[16], z1r[16], z2r[16], z3r[16];
    if (tid < 100) {
#pragma unroll
        for (int u = 0; u < 16; ++u) {
            z0[u]  = zb[u * 100];
            z1r[u] = zb[(16 + u) * 100];
            z2r[u] = zb[(32 + u) * 100];
            z3r[u] = zb[(48 + u) * 100];
        }
    }

    const int tg = tid - 128;
    int pp = tg >> 7;                                     // wave-uniform for tid>=128
    pp = __builtin_amdgcn_readfirstlane(pp);
    const int r  = tg & 127;
    const int mb = (pp == 0) ? 0 : (pp == 1 ? 4 : 7);
    const int mc = (pp == 0) ? 4 : 3;

    for (int i = 0; i <= 18; ++i) {
        if (tid < 128) {
            bool a1 = (tid < 100) && (i < 16);
            bool a2 = (tid >= 100) && (tid < 110) && (i >= 2) && (i < 18);
            if (a1 || a2) {
                const int cw = i & 1;
#pragma unroll
                for (int sub = 0; sub < 8; ++sub) {
                    float zt[16];
                    if (a1) {
                        int tn = (i * 8 + sub + 4) * 16;
                        if (tn < 2048) {
#pragma unroll
                            for (int u = 0; u < 16; ++u) zt[u] = zb[(tn + u) * 100];
                        }
                    }
                    if (a2) {
#pragma unroll
                        for (int u = 0; u < 16; ++u)
                            z0[u] = fsm[29696 + cw * 1536 + (sub * 16 + u) * 12 + (tid - 100)];
                    }
#pragma unroll
                    for (int u = 0; u < 16; ++u) {
                        int tl = sub * 16 + u;
                        fsm[cw * 14848 + tl * 116 + tid] = V;
                        float z  = z0[u];
                        float V3 = V * V * V;
                        float Vn = fmaf(1.f + dt, V,
                                    fmaf(-dt / 3.f, V3, fmaf(-dt, S, dt * z)));
                        float Sn = fmaf(dt * 0.08f, V + 0.7f - 0.8f * S, S);
                        V = Vn; S = Sn;
                    }
                    if (a1) {
#pragma unroll
                        for (int u = 0; u < 16; ++u) {
                            z0[u] = z1r[u]; z1r[u] = z2r[u]; z2r[u] = z3r[u]; z3r[u] = zt[u];
                        }
                    }
                }
            }
        } else {
            if (i >= 1 && i <= 16) {
                const int pb = (i - 1) & 1;
                float acc[4] = {0.f, 0.f, 0.f, 0.f};
                for (int kq = 0; kq < 25; ++kq) {
                    float4 v = *(const float4*)&fsm[pb * 14848 + r * 116 + kq * 4];
#pragma unroll
                    for (int j = 0; j < 4; ++j) {
                        if (j < mc) {
                            const float* wp = W2 + (mb + j) * 100 + kq * 4;  // uniform -> s_load
                            acc[j] = fmaf(v.x, wp[0], acc[j]);
                            acc[j] = fmaf(v.y, wp[1], acc[j]);
                            acc[j] = fmaf(v.z, wp[2], acc[j]);
                            acc[j] = fmaf(v.w, wp[3], acc[j]);
                        }
                    }
                }
#pragma unroll
                for (int j = 0; j < 4; ++j)
                    if (j < mc) fsm[29696 + pb * 1536 + r * 12 + mb + j] = 0.5f * acc[j];
            }
            if (i >= 3) {
                const int pb = (i - 1) & 1;
                float* dst = out + ((long)b * 2048 + (long)(i - 3) * 128 + r) * 10;
#pragma unroll
                for (int j = 0; j < 4; ++j)
                    if (j < mc) dst[mb + j] = fsm[pb * 14848 + r * 116 + 100 + mb + j];
            }
        }
        sync_lds();
    }
}

extern "C" void kernel_launch(void* const* d_in, const int* in_sizes, int n_in,
                              void* d_out, int out_size, void* d_ws, size_t ws_size,
                              hipStream_t stream) {
    const float* batch = (const float*)d_in[0];   // 64*2048*784
    const float* W1    = (const float*)d_in[1];   // 100*784
    const float* W2    = (const float*)d_in[2];   // 10*100
    float* out = (float*)d_out;                   // 64*2048*10

    char* base = (char*)d_ws;
    unsigned short* Wg = (unsigned short*)base;   // 448000 B
    float* z1p = (float*)(base + 448000);         // 131072*100 f32

    prep_w3<<<875, 256, 0, stream>>>(W1, Wg);
    gemm1_f<<<2048, 256, 0, stream>>>(batch, Wg, z1p);
    fused_scan<<<64, 512, 0, stream>>>(z1p, W2, out);
}

// Round 7
// 232.882 us; speedup vs baseline: 1.6684x; 1.0168x over previous
//
#include <hip/hip_runtime.h>
#include <hip/hip_bf16.h>

// B=64, T=2048, D=784, N1=100, N2=10, dt=0.04
// Pipeline:
//   prep_w3  : W1 -> fp16 2-way split (h, r*1024), per-K-tile linear image
//              [kt=25][18432 B]: [term 2][n 112][40 shorts(32 data+8 pad)] + 512 B pad
//   gemm1_g  : z1 = batch @ W1^T, 3-term fp16 split MFMA (acc2 scaled 2^-10).
//              BM=64, 256 thr. ALL staging via global_load_lds (no reg staging,
//              no ds_writes): A triple-buffered (2-iter cover, XOR-swizzled via
//              pre-swizzled global source), W double-buffered (1-iter cover).
//              One raw s_barrier + counted vmcnt(2) per iter (vmcnt(0) only at
//              the last iter). LDS 61440 B -> 2 blocks/CU.
//   fused_scan: scan1 + gemm2 + scan2 in one kernel (round-6 version verbatim).
//
// ws: Wg 460800 B | z1p 131072*100 f32 (52.4 MB)

#define FHN_DT 0.04f

typedef _Float16 f16x8 __attribute__((ext_vector_type(8)));
typedef __attribute__((ext_vector_type(4))) float f32x4;

__device__ __forceinline__ void gl16(const void* g, void* l) {
    __builtin_amdgcn_global_load_lds(
        (const __attribute__((address_space(1))) unsigned int*)g,
        (__attribute__((address_space(3))) unsigned int*)l, 16, 0, 0);
}

#define VMW(N) asm volatile("s_waitcnt vmcnt(" #N ")" ::: "memory")

__device__ __forceinline__ void sync_lds() {
    asm volatile("s_waitcnt lgkmcnt(0)" ::: "memory");
    __builtin_amdgcn_s_barrier();
    asm volatile("" ::: "memory");
}

// ---------------- prep: W1 (100x784) -> tiled fp16 2-term split image ----------------
__global__ void prep_w3(const float* __restrict__ W1, unsigned short* __restrict__ Wg) {
    int idx = blockIdx.x * 256 + threadIdx.x;     // < 25*9216 = 230400 shorts
    if (idx >= 230400) return;
    int kt  = idx / 9216;
    int rem = idx % 9216;
    unsigned short v16 = 0;
    if (rem < 8960) {
        int term = rem / 4480;
        int r2   = rem % 4480;
        int n    = r2 / 40;
        int sh   = r2 % 40;
        int k    = kt * 32 + sh;
        float v = (n < 100 && sh < 32 && k < 784) ? W1[n * 784 + k] : 0.0f;
        _Float16 h = (_Float16)v;
        if (term == 0) v16 = __builtin_bit_cast(unsigned short, h);
        else           v16 = __builtin_bit_cast(unsigned short, (_Float16)((v - (float)h) * 1024.0f));
    }
    Wg[idx] = v16;
}

// ---------------- GEMM1: 3-term fp16 split, BM=64, BK=32, 4 waves, all-DMA staging ----------------
// LDS: A bufs 3 x 8192 @0 (swizzled [row 64][128 B], byte^=(row&7)<<4 on bits 4-6)
//      W bufs 2 x 18432 @24576 ([term 2][n 112][80 B], linear = ws image)
__global__ __launch_bounds__(256, 2) void gemm1_g(const float* __restrict__ A,
                                                  const unsigned short* __restrict__ Wg,
                                                  float* __restrict__ z1p) {
    __shared__ __align__(16) char smem[61440];
    const int tid  = threadIdx.x;
    const int w    = tid >> 6;
    const int lane = tid & 63;
    const int ln   = lane & 15;
    const int kg   = lane >> 4;
    const long row0 = (long)blockIdx.x * 64;
    const bool wlo = (w < 2);

    // A DMA sources: 2 chunks/wave, chunk c = w*2+r; LDS d = c*1024 + lane*16;
    // row = d>>7, logical inner L = (d&127) ^ ((row&7)<<4)  (inverse-swizzled source)
    const char* abase[2];
    const char* abase24[2];   // kt=24 tail: L>=64 re-reads L-64 (finite; W-pad is 0)
#pragma unroll
    for (int r = 0; r < 2; ++r) {
        int c = w * 2 + r;
        int d = c * 1024 + lane * 16;
        int row = d >> 7;
        int L = (d & 127) ^ ((row & 7) << 4);
        abase[r]   = (const char*)(A + (size_t)(row0 + row) * 784) + L;
        abase24[r] = (L >= 64) ? (abase[r] - 64) : abase[r];
    }

    f32x4 acc1[7] = {};
    f32x4 acc2[7] = {};

#define ISSUE_A(t)                                                              \
    {                                                                           \
        char* bufA_ = smem + ((t) % 3) * 8192;                                  \
        const char* s0_ = ((t) == 24) ? abase24[0] : abase[0];                  \
        const char* s1_ = ((t) == 24) ? abase24[1] : abase[1];                  \
        gl16(s0_ + (t) * 128, bufA_ + (w * 2 + 0) * 1024);                      \
        gl16(s1_ + (t) * 128, bufA_ + (w * 2 + 1) * 1024);                      \
    }

#define ISSUE_W(t)                                                              \
    {                                                                           \
        char* bufW_ = smem + 24576 + ((t) & 1) * 18432;                         \
        const char* src_ = (const char*)Wg + (size_t)(t) * 18432 + lane * 16;   \
        _Pragma("unroll")                                                       \
        for (int j_ = 0; j_ < 5; ++j_) {                                        \
            int c_ = w + j_ * 4;                                                \
            if (j_ < 4 || wlo) gl16(src_ + c_ * 1024, bufW_ + c_ * 1024);       \
        }                                                                       \
    }

    // prologue: A(0)->buf0, W(0)->wbuf0, A(1)->buf1  (A1 newest => vmcnt(2) at kt=0)
    ISSUE_A(0);
    ISSUE_W(0);
    ISSUE_A(1);

    for (int kt = 0; kt < 25; ++kt) {
        // counted wait: keep only the newest 2 (next A tile's chunks) in flight;
        // drains this tile's A and W DMAs. Last iter: drain all.
        if (kt == 24) { VMW(0); } else { VMW(2); }
        __builtin_amdgcn_s_barrier();
        asm volatile("" ::: "memory");

        // issue next tiles AFTER the barrier: previous readers of the target
        // buffers finished (their MFMAs consumed the data before reaching B).
        if (kt < 24) ISSUE_W(kt + 1);
        if (kt < 23) ISSUE_A(kt + 2);

        // ---- compute tile kt ----
        const char* bufA = smem + (kt % 3) * 8192;
        const char* bufW = smem + 24576 + (kt & 1) * 18432;
        const int row = w * 16 + ln;
        const int s = (ln & 7) << 4;
        f32x4 a0 = *(const f32x4*)(bufA + row * 128 + ((kg * 32) ^ s));
        f32x4 a1 = *(const f32x4*)(bufA + row * 128 + ((kg * 32 + 16) ^ s));
        float av[8] = {a0[0], a0[1], a0[2], a0[3], a1[0], a1[1], a1[2], a1[3]};
        f16x8 ah, al;
#pragma unroll
        for (int e = 0; e < 8; ++e) {
            _Float16 h = (_Float16)av[e];
            ah[e] = h;
            al[e] = (_Float16)((av[e] - (float)h) * 1024.0f);
        }
#pragma unroll
        for (int ct = 0; ct < 7; ++ct) {
            const char* pw = bufW + (ct * 16 + ln) * 80 + kg * 16;
            f16x8 bh = *(const f16x8*)(pw);
            f16x8 bl = *(const f16x8*)(pw + 8960);
            acc1[ct] = __builtin_amdgcn_mfma_f32_16x16x32_f16(ah, bh, acc1[ct], 0, 0, 0);
            acc2[ct] = __builtin_amdgcn_mfma_f32_16x16x32_f16(ah, bl, acc2[ct], 0, 0, 0);
            acc2[ct] = __builtin_amdgcn_mfma_f32_16x16x32_f16(al, bh, acc2[ct], 0, 0, 0);
        }
    }

    // ---- epilogue: C/D map col = lane&15, row = kg*4 + r ; z = acc1 + acc2/1024 ----
#pragma unroll
    for (int ct = 0; ct < 7; ++ct) {
        int n = ct * 16 + ln;
        if (n < 100) {
            long rg = row0 + w * 16 + kg * 4;
            float* p = z1p + rg * 100 + n;
#pragma unroll
            for (int r = 0; r < 4; ++r)
                p[r * 100] = fmaf(acc2[ct][r], 0.0009765625f, acc1[ct][r]);
        }
    }
#undef ISSUE_A
#undef ISSUE_W
}

// ---------------- fused scan1 + gemm2 + scan2 (round-6 version, unchanged) ----------------
__global__ __launch_bounds__(512) void fused_scan(const float* __restrict__ z1p,
                                                  const float* __restrict__ W2,
                                                  float* __restrict__ out) {
    __shared__ float fsm[32768];
    const int tid = threadIdx.x;
    const int b   = blockIdx.x;
    const float dt = FHN_DT;

    float V = 0.f, S = 0.f;
    const float* zb = z1p + (long)b * 2048 * 100 + tid;   // scan1 lanes only
    float z0[16], z1r[16], z2r[16], z3r[16];
    if (tid < 100) {
#pragma unroll
        for (int u = 0; u < 16; ++u) {
            z0[u]  = zb[u * 100];
            z1r[u] = zb[(16 + u) * 100];
            z2r[u] = zb[(32 + u) * 100];
            z3r[u] = zb[(48 + u) * 100];
        }
    }

    const int tg = tid - 128;
    int pp = tg >> 7;                                     // wave-uniform for tid>=128
    pp = __builtin_amdgcn_readfirstlane(pp);
    const int r  = tg & 127;
    const int mb = (pp == 0) ? 0 : (pp == 1 ? 4 : 7);
    const int mc = (pp == 0) ? 4 : 3;

    for (int i = 0; i <= 18; ++i) {
        if (tid < 128) {
            bool a1 = (tid < 100) && (i < 16);
            bool a2 = (tid >= 100) && (tid < 110) && (i >= 2) && (i < 18);
            if (a1 || a2) {
                const int cw = i & 1;
#pragma unroll
                for (int sub = 0; sub < 8; ++sub) {
                    float zt[16];
                    if (a1) {
                        int tn = (i * 8 + sub + 4) * 16;
                        if (tn < 2048) {
#pragma unroll
                            for (int u = 0; u < 16; ++u) zt[u] = zb[(tn + u) * 100];
                        }
                    }
                    if (a2) {
#pragma unroll
                        for (int u = 0; u < 16; ++u)
                            z0[u] = fsm[29696 + cw * 1536 + (sub * 16 + u) * 12 + (tid - 100)];
                    }
#pragma unroll
                    for (int u = 0; u < 16; ++u) {
                        int tl = sub * 16 + u;
                        fsm[cw * 14848 + tl * 116 + tid] = V;
                        float z  = z0[u];
                        float V3 = V * V * V;
                        float Vn = fmaf(1.f + dt, V,
                                    fmaf(-dt / 3.f, V3, fmaf(-dt, S, dt * z)));
                        float Sn = fmaf(dt * 0.08f, V + 0.7f - 0.8f * S, S);
                        V = Vn; S = Sn;
                    }
                    if (a1) {
#pragma unroll
                        for (int u = 0; u < 16; ++u) {
                            z0[u] = z1r[u]; z1r[u] = z2r[u]; z2r[u] = z3r[u]; z3r[u] = zt[u];
                        }
                    }
                }
            }
        } else {
            if (i >= 1 && i <= 16) {
                const int pb = (i - 1) & 1;
                float acc[4] = {0.f, 0.f, 0.f, 0.f};
                for (int kq = 0; kq < 25; ++kq) {
                    float4 v = *(const float4*)&fsm[pb * 14848 + r * 116 + kq * 4];
#pragma unroll
                    for (int j = 0; j < 4; ++j) {
                        if (j < mc) {
                            const float* wp = W2 + (mb + j) * 100 + kq * 4;  // uniform -> s_load
                            acc[j] = fmaf(v.x, wp[0], acc[j]);
                            acc[j] = fmaf(v.y, wp[1], acc[j]);
                            acc[j] = fmaf(v.z, wp[2], acc[j]);
                            acc[j] = fmaf(v.w, wp[3], acc[j]);
                        }
                    }
                }
#pragma unroll
                for (int j = 0; j < 4; ++j)
                    if (j < mc) fsm[29696 + pb * 1536 + r * 12 + mb + j] = 0.5f * acc[j];
            }
            if (i >= 3) {
                const int pb = (i - 1) & 1;
                float* dst = out + ((long)b * 2048 + (long)(i - 3) * 128 + r) * 10;
#pragma unroll
                for (int j = 0; j < 4; ++j)
                    if (j < mc) dst[mb + j] = fsm[pb * 14848 + r * 116 + 100 + mb + j];
            }
        }
        sync_lds();
    }
}

extern "C" void kernel_launch(void* const* d_in, const int* in_sizes, int n_in,
                              void* d_out, int out_size, void* d_ws, size_t ws_size,
                              hipStream_t stream) {
    const float* batch = (const float*)d_in[0];   // 64*2048*784
    const float* W1    = (const float*)d_in[1];   // 100*784
    const float* W2    = (const float*)d_in[2];   // 10*100
    float* out = (float*)d_out;                   // 64*2048*10

    char* base = (char*)d_ws;
    unsigned short* Wg = (unsigned short*)base;   // 460800 B
    float* z1p = (float*)(base + 460800);         // 131072*100 f32

    prep_w3<<<900, 256, 0, stream>>>(W1, Wg);
    gemm1_g<<<2048, 256, 0, stream>>>(batch, Wg, z1p);
    fused_scan<<<64, 512, 0, stream>>>(z1p, W2, out);
}